// Round 3
// baseline (187.783 us; speedup 1.0000x reference)
//
#include <hip/hip_runtime.h>
#include <hip/hip_fp16.h>

// Volume: [B=2, X=128, Y=128, Z=128, C=1] fp32, grid: [B, N=2^21, 3] in [0,1].
// Output: [B, N, 1] fp32 trilinear samples.
// image flat index = b*2^21 + x*2^14 + y*2^7 + z  (z fastest).
//
// R2: fp16 volume in d_ws -> FETCH 594->127 MB, 180->132 us.
// R3: z-pair gathers (4 divergent loads/sample) + XCD batch-parity swizzle.
// R4: corner-cube record layout: 16B record/voxel holds all 8 corners ->
//     ONE 16B gather/sample. Sampler 90->77 us, FETCH 112->255 MB (records
//     33.5 MB/batch vs 4 MB L2/XCD -> ~75% L2 miss, fills from L3).
// R5: rocprof on R4: VALU 6%, occ 70%, 45% HBM, requests 4x below R3's
//     sustained rate -> NOT request- or VALU-bound. Little's law: 1
//     outstanding gather/wave x ~600cy L3 latency x ~22 waves/CU ~= 64 us
//     -> latency/MSHR-bound. Fix: ILP=4 samples/thread -> 4 independent
//     gathers in flight per wave (4x MLP), grid read becomes 3x dwordx4
//     contiguous per thread, out becomes one float4 store.
// R6: R5 failed to compile: __builtin_nontemporal_load rejects
//     HIP_vector_type (float4 is a class). Use clang ext_vector_type(4)
//     floats for the nontemporal load/store paths. Same codegen otherwise.

#define TOTAL   (2 * 2097152)   // B * N samples
#define LOG2N   21              // N = 2^21 per batch; VOL = 2^21 voxels too
#define VOL     (128 * 128 * 128)
#define NVOX    (2 * VOL)

typedef __attribute__((ext_vector_type(4))) float fx4;   // nontemporal-OK

// ---- R5 pre-pass: fp32 volume -> 16B corner-cube records, 4 voxels/thread
// rec[b,x,y,z] = { h2(c[x,y,z],   c[x,y,z+1]),      // q11 z-pair
//                  h2(c[x+1,y,z], c[x+1,y,z+1]),    // q21
//                  h2(c[x,y+1,z], c[x,y+1,z+1]),    // q12
//                  h2(c[x+1,y+1,z], c[x+1,y+1,z+1]) } // q22
// (+1 clamped at 127; x==127 / y==127 / z==127 records never read by the
//  sampler since clip() keeps floor() <= 126, but filled consistently.)
__global__ __launch_bounds__(256)
void ImageWarped_build_rec4_kernel(const float* __restrict__ in,
                                   uint4* __restrict__ rec)
{
    const int t    = blockIdx.x * 256 + threadIdx.x;  // NVOX/4 threads
    const int idx0 = t << 2;                          // 4 voxels along z
    const int v    = idx0 & (VOL - 1);
    const int x    = v >> 14;
    const int y    = (v >> 7) & 127;
    const int z0   = v & 127;                         // multiple of 4, 0..124
    const int xo   = (x < 127) ? (1 << 14) : 0;
    const int yo   = (y < 127) ? (1 << 7)  : 0;

    const float* __restrict__ r11 = in + (idx0 - z0); // row base (incl batch)
    const float* __restrict__ r21 = r11 + xo;
    const float* __restrict__ r12 = r11 + yo;
    const float* __restrict__ r22 = r21 + yo;

    const int zn = min(z0 + 4, 127);                  // clamped next value
    const float4 a11 = *(const float4*)(r11 + z0); const float e11 = r11[zn];
    const float4 a21 = *(const float4*)(r21 + z0); const float e21 = r21[zn];
    const float4 a12 = *(const float4*)(r12 + z0); const float e12 = r12[zn];
    const float4 a22 = *(const float4*)(r22 + z0); const float e22 = r22[zn];

    union { __half2 h; unsigned u; } p;
    #define PAIR(lo, hi) (p.h = __floats2half2_rn((lo), (hi)), p.u)
    // k=0: (v.x,v.y)  k=1: (v.y,v.z)  k=2: (v.z,v.w)  k=3: (v.w,e)
    rec[idx0 + 0] = make_uint4(PAIR(a11.x, a11.y), PAIR(a21.x, a21.y),
                               PAIR(a12.x, a12.y), PAIR(a22.x, a22.y));
    rec[idx0 + 1] = make_uint4(PAIR(a11.y, a11.z), PAIR(a21.y, a21.z),
                               PAIR(a12.y, a12.z), PAIR(a22.y, a22.z));
    rec[idx0 + 2] = make_uint4(PAIR(a11.z, a11.w), PAIR(a21.z, a21.w),
                               PAIR(a12.z, a12.w), PAIR(a22.z, a22.w));
    rec[idx0 + 3] = make_uint4(PAIR(a11.w, e11),   PAIR(a21.w, e21),
                               PAIR(a12.w, e12),   PAIR(a22.w, e22));
    #undef PAIR
}

// ---- R5 main: 4 samples/thread, 4 independent 16B gathers in flight ------
struct SampleW { int base; float wx, wx2, wy, wy2, wz, wz2; };

__device__ __forceinline__ SampleW mk_sample(float gx, float gy, float gz)
{
    SampleW s;
    // idx = clip(grid * 128, 0.001, 126.999)
    const float xf = fminf(fmaxf(gx * 128.0f, 0.001f), 126.999f);
    const float yf = fminf(fmaxf(gy * 128.0f, 0.001f), 126.999f);
    const float zf = fminf(fmaxf(gz * 128.0f, 0.001f), 126.999f);
    const float x1f = floorf(xf), x2f = ceilf(xf);
    const float y1f = floorf(yf), y2f = ceilf(yf);
    const float z1f = floorf(zf), z2f = ceilf(zf);
    // Literal two-weight form: if a coord is integral both weights are 0
    // (reference semantics), NOT w/1-w.
    s.wx = xf - x1f; s.wx2 = x2f - xf;
    s.wy = yf - y1f; s.wy2 = y2f - yf;
    s.wz = zf - z1f; s.wz2 = z2f - zf;
    s.base = ((int)x1f << 14) + ((int)y1f << 7) + (int)z1f;
    return s;
}

__device__ __forceinline__ float fold_sample(const uint4 u, const SampleW& s)
{
    union { unsigned u32; __half2 h; } c;
    c.u32 = u.x; const float2 f11 = __half22float2(c.h);
    c.u32 = u.y; const float2 f21 = __half22float2(c.h);
    c.u32 = u.z; const float2 f12 = __half22float2(c.h);
    c.u32 = u.w; const float2 f22 = __half22float2(c.h);
    const float q11 = f11.x * s.wz2 + f11.y * s.wz;   // z-lerp, literal form
    const float q21 = f21.x * s.wz2 + f21.y * s.wz;
    const float q12 = f12.x * s.wz2 + f12.y * s.wz;
    const float q22 = f22.x * s.wz2 + f22.y * s.wz;
    // multilinear expansion == reference up to FP reassociation
    return (q21 * s.wx + q11 * s.wx2) * s.wy2
         + (q22 * s.wx + q12 * s.wx2) * s.wy;
}

__global__ __launch_bounds__(256)
void ImageWarped_trilinear_rec4_kernel(const uint4* __restrict__ rec,
                                       const float* __restrict__ grid,
                                       float* __restrict__ out)
{
    // Batch-parity swizzle: round-robin blockIdx%8 -> XCD means each XCD's
    // L2 only sees ONE batch's record set.
    const int batch = blockIdx.x & 1;
    const int g     = (blockIdx.x >> 1) * 256 + threadIdx.x;  // sample group
    const int i0    = (batch << LOG2N) | (g << 2);            // 1st sample

    // 48B contiguous grid per thread; nontemporal: read-once stream, keep
    // it from evicting record lines in L2.
    const fx4* gp = (const fx4*)(grid + 3 * (size_t)i0);
    const fx4 a = __builtin_nontemporal_load(gp + 0);
    const fx4 b = __builtin_nontemporal_load(gp + 1);
    const fx4 d = __builtin_nontemporal_load(gp + 2);

    const uint4* __restrict__ rb = rec + ((size_t)batch << LOG2N);

    const SampleW s0 = mk_sample(a.x, a.y, a.z);
    const SampleW s1 = mk_sample(a.w, b.x, b.y);
    const SampleW s2 = mk_sample(b.z, b.w, d.x);
    const SampleW s3 = mk_sample(d.y, d.z, d.w);

    // 4 independent divergent gathers issued back-to-back -> 4x MLP/wave.
    const uint4 u0 = rb[s0.base];
    const uint4 u1 = rb[s1.base];
    const uint4 u2 = rb[s2.base];
    const uint4 u3 = rb[s3.base];

    fx4 r;
    r.x = fold_sample(u0, s0);
    r.y = fold_sample(u1, s1);
    r.z = fold_sample(u2, s2);
    r.w = fold_sample(u3, s3);
    __builtin_nontemporal_store(r, (fx4*)(out + i0));
}

// ---- R3 pre-pass (fallback): fp32 volume -> fp16 volume ------------------
__global__ __launch_bounds__(256)
void ImageWarped_cvt_fp16_kernel(const float* __restrict__ in,
                                 __half* __restrict__ out)
{
    const int i = blockIdx.x * 256 + threadIdx.x;   // NVOX/4 threads
    const float4 v = ((const float4*)in)[i];
    union { __half2 h2[2]; uint2 u; } p;
    p.h2[0] = __floats2half2_rn(v.x, v.y);
    p.h2[1] = __floats2half2_rn(v.z, v.w);
    ((uint2*)out)[i] = p.u;
}

// ---- R3 main (fallback): trilinear gather, z-pairs via 8B windows --------
__global__ __launch_bounds__(256)
void ImageWarped_trilinear_h2_kernel(const __half* __restrict__ image,
                                     const float* __restrict__ grid,
                                     float* __restrict__ out)
{
    const int batch = blockIdx.x & 1;
    const int s     = (blockIdx.x >> 1) * 256 + threadIdx.x;
    const int i     = (batch << LOG2N) | s;

    const float gx = grid[3 * i + 0];
    const float gy = grid[3 * i + 1];
    const float gz = grid[3 * i + 2];

    const __half* __restrict__ img = image + ((size_t)batch << LOG2N);

    const float xf = fminf(fmaxf(gx * 128.0f, 0.001f), 126.999f);
    const float yf = fminf(fmaxf(gy * 128.0f, 0.001f), 126.999f);
    const float zf = fminf(fmaxf(gz * 128.0f, 0.001f), 126.999f);

    const float x1f = floorf(xf), x2f = ceilf(xf);
    const float y1f = floorf(yf), y2f = ceilf(yf);
    const float z1f = floorf(zf), z2f = ceilf(zf);

    const float wx  = xf - x1f, wx2 = x2f - xf;
    const float wy  = yf - y1f, wy2 = y2f - yf;
    const float wz  = zf - z1f, wz2 = z2f - zf;

    const int ix1 = (int)x1f, ix2 = (int)x2f;
    const int iy1 = (int)y1f, iy2 = (int)y2f;
    const int iz1 = (int)z1f;

    const int bx1 = ix1 << 14, bx2 = ix2 << 14;
    const int by1 = iy1 << 7,  by2 = iy2 << 7;

    const int ze = min(iz1 & ~1, 124);
    const int sh = (iz1 - ze) << 4;

    const float  ww  = wz2, wwz = wz;
    auto zfetch = [&](int off) -> float {
        const uint2 u = *(const uint2*)(img + off + ze);
        unsigned long long w = ((unsigned long long)u.y << 32) | u.x;
        w >>= sh;
        union { unsigned int u32; __half2 h; } c;
        c.u32 = (unsigned int)w;
        const float2 f = __half22float2(c.h);
        return f.x * ww + f.y * wwz;
    };

    const float q11 = zfetch(bx1 + by1);
    const float q21 = zfetch(bx2 + by1);
    const float q12 = zfetch(bx1 + by2);
    const float q22 = zfetch(bx2 + by2);

    out[i] = (q21 * wx + q11 * wx2) * wy2
           + (q22 * wx + q12 * wx2) * wy;
}

// ---- fallback (R1 kernel, fp32 gathers) if ws too small ------------------
__global__ __launch_bounds__(256)
void ImageWarped_trilinear_f_kernel(const float* __restrict__ image,
                                    const float* __restrict__ grid,
                                    float* __restrict__ out)
{
    const int i = blockIdx.x * 256 + threadIdx.x;
    if (i >= TOTAL) return;

    const float gx = grid[3 * i + 0];
    const float gy = grid[3 * i + 1];
    const float gz = grid[3 * i + 2];

    const int b = i >> LOG2N;
    const float* __restrict__ img = image + (size_t)b * VOL;

    const float xf = fminf(fmaxf(gx * 128.0f, 0.001f), 126.999f);
    const float yf = fminf(fmaxf(gy * 128.0f, 0.001f), 126.999f);
    const float zf = fminf(fmaxf(gz * 128.0f, 0.001f), 126.999f);

    const float x1f = floorf(xf), x2f = ceilf(xf);
    const float y1f = floorf(yf), y2f = ceilf(yf);
    const float z1f = floorf(zf), z2f = ceilf(zf);

    const float wx  = xf - x1f, wx2 = x2f - xf;
    const float wy  = yf - y1f, wy2 = y2f - yf;
    const float wz  = zf - z1f, wz2 = z2f - zf;

    const int ix1 = (int)x1f, ix2 = (int)x2f;
    const int iy1 = (int)y1f, iy2 = (int)y2f;
    const int iz1 = (int)z1f, iz2 = (int)z2f;

    const int bx1 = ix1 << 14, bx2 = ix2 << 14;
    const int by1 = iy1 << 7,  by2 = iy2 << 7;

    const float c111 = img[bx1 + by1 + iz1];
    const float c211 = img[bx2 + by1 + iz1];
    const float c121 = img[bx1 + by2 + iz1];
    const float c221 = img[bx2 + by2 + iz1];
    const float c112 = img[bx1 + by1 + iz2];
    const float c212 = img[bx2 + by1 + iz2];
    const float c122 = img[bx1 + by2 + iz2];
    const float c222 = img[bx2 + by2 + iz2];

    const float lerp_y1 = (c211 * wx + c111 * wx2) * wy2
                        + (c221 * wx + c121 * wx2) * wy;
    const float lerp_y2 = (c212 * wx + c112 * wx2) * wy2
                        + (c222 * wx + c122 * wx2) * wy;

    out[i] = lerp_y2 * wz + lerp_y1 * wz2;
}

extern "C" void kernel_launch(void* const* d_in, const int* in_sizes, int n_in,
                              void* d_out, int out_size, void* d_ws, size_t ws_size,
                              hipStream_t stream)
{
    const float* image = (const float*)d_in[0];  // [2,128,128,128,1] fp32
    const float* grid  = (const float*)d_in[1];  // [2,2097152,3]     fp32
    float* out = (float*)d_out;                  // [2,2097152,1]     fp32

    if (ws_size >= (size_t)NVOX * sizeof(uint4)) {          // 67.1 MB
        uint4* rec = (uint4*)d_ws;
        ImageWarped_build_rec4_kernel<<<NVOX / 4 / 256, 256, 0, stream>>>(image, rec);
        ImageWarped_trilinear_rec4_kernel<<<TOTAL / 4 / 256, 256, 0, stream>>>(rec, grid, out);
    } else if (ws_size >= (size_t)NVOX * sizeof(__half)) {  // 8.4 MB
        __half* img16 = (__half*)d_ws;
        ImageWarped_cvt_fp16_kernel<<<NVOX / 4 / 256, 256, 0, stream>>>(image, img16);
        ImageWarped_trilinear_h2_kernel<<<(TOTAL + 255) / 256, 256, 0, stream>>>(img16, grid, out);
    } else {
        ImageWarped_trilinear_f_kernel<<<(TOTAL + 255) / 256, 256, 0, stream>>>(image, grid, out);
    }
}